// Round 18
// baseline (228.521 us; speedup 1.0000x reference)
//
#include <hip/hip_runtime.h>
#include <stdint.h>

#define D_DIM 4096
#define N_ROWS 8192

typedef __attribute__((ext_vector_type(8))) short bfrag8;
typedef __attribute__((ext_vector_type(4))) float facc4;
typedef unsigned long long u64;

union ABfrag { uint32_t u[4]; bfrag8 b; };

__device__ __forceinline__ uint32_t pack_bf16x2(float lo, float hi) {
    union { float f; uint32_t u; } a, b;
    a.f = lo; b.f = hi;
    return (b.u & 0xFFFF0000u) | (a.u >> 16);   // truncate-to-bf16
}

// ---------------------------------------------------------------------------
// Kernel 0: A fp32 -> bf16, XOR-swizzled per-K-chunk image (verified).
// ---------------------------------------------------------------------------
__global__ void __launch_bounds__(256)
prep_A(const float* __restrict__ A, uint32_t* __restrict__ A_sw) {
    const int S = blockIdx.x * 256 + threadIdx.x;  // 0..65535
    const int c = S >> 10;
    const int s = S & 1023;
    const int n = s >> 3;
    const int g = (s & 7) ^ (n & 7);
    const float* src = A + (size_t)n * D_DIM + c * 64 + g * 8;
    float4 f0 = *(const float4*)(src);
    float4 f1 = *(const float4*)(src + 4);
    uint4 o;
    o.x = pack_bf16x2(f0.x, f0.y);
    o.y = pack_bf16x2(f0.z, f0.w);
    o.z = pack_bf16x2(f1.x, f1.y);
    o.w = pack_bf16x2(f1.z, f1.w);
    *(uint4*)(A_sw + (size_t)S * 4) = o;
}

// ---------------------------------------------------------------------------
// Kernel 1: split-K GEMM, BM=64, 2-PHASE double-buffered gload_lds staging.
// R14 proved gload_lds staging (un-sinkable loads); R17 proved blocks/CU
// is NOT binding (2/CU == 4/CU). Remaining slack = the 1-phase schedule:
// STAGE -> immediate vmcnt(0) drain exposes the whole fetch. This round
// applies the guide's minimum 2-phase (T3/m97 pattern): issue NEXT tile's
// loads BEFORE computing current tile; ONE barrier per K-step; the
// pre-barrier drain then lands after a full compute phase of overlap.
//   prologue: STAGE(buf0); sync;
//   loop t<kpb-1: STAGE(buf^1, t+1); COMPUTE(buf); sync; flip;
//   epilogue: COMPUTE(buf)  (no prefetch)
// Race audit: stage(buf^1)@t vs readers of buf^1@t-1 separated by t-1's
// ending barrier (full vmcnt+lgkm drain). Compute body, both swizzles,
// partials/C-D layouts = R14/R17 HW-verified code, untouched.
// S=4 (kpb=16): halves partials traffic, deepens pipeline. LDS 64 KB,
// grid (4,128)=512 blocks = 2/CU.
// ---------------------------------------------------------------------------
__global__ void __launch_bounds__(256, 2)
gemm_split64_db(const float* __restrict__ L, const uint32_t* __restrict__ A_sw,
                float* __restrict__ partials, int kpb) {
    __shared__ uint32_t Lf[2][4096];  // 2 x 16 KB: 64 rows x 16 slots x 16B fp32
    __shared__ uint4    As[2][1024];  // 2 x 16 KB: B chunk (verified swizzle)

    const int tid  = threadIdx.x;
    const int wave = tid >> 6;
    const int lane = tid & 63;
    const int split = blockIdx.x;
    const int row0 = blockIdx.y * 64;
    const int c  = lane & 15;
    const int q  = lane >> 4;
    const int wm = wave >> 1;         // 32-row half
    const int wn = wave & 1;          // 64-col half

    // L-staging geometry (wave-uniform dst, per-lane swizzled src) [verified].
    const int lrow_lo = wave * 4 + (lane >> 4);          // 0..15
    const int js      = (lane & 15) ^ (lrow_lo & 7);     // src 16B-slot in row
    const float* lsrc0 = L + (size_t)(row0 + lrow_lo) * D_DIM + js * 4;

    facc4 acc[2][4];
#pragma unroll
    for (int m = 0; m < 2; m++)
#pragma unroll
        for (int ct = 0; ct < 4; ct++) acc[m][ct] = (facc4){0.f, 0.f, 0.f, 0.f};

    const int kc0 = split * kpb * 64;

    auto stage = [&](int d, int kc) {
        const uint32_t* gA = A_sw + (size_t)(kc >> 6) * 4096;
#pragma unroll
        for (int i = 0; i < 4; i++) {
            const int slot0 = wave * 256 + i * 64;
            __builtin_amdgcn_global_load_lds(
                (const __attribute__((address_space(1))) uint32_t*)(gA + (slot0 + lane) * 4),
                (__attribute__((address_space(3))) uint32_t*)(&As[d][slot0]),
                16, 0, 0);
        }
#pragma unroll
        for (int i = 0; i < 4; i++) {
            const uint32_t* src = (const uint32_t*)(lsrc0 + (size_t)(i * 16) * D_DIM + kc);
            __builtin_amdgcn_global_load_lds(
                (const __attribute__((address_space(1))) uint32_t*)src,
                (__attribute__((address_space(3))) uint32_t*)(&Lf[d][(i * 256 + wave * 64) * 4]),
                16, 0, 0);
        }
    };

    auto compute = [&](int d) {
#pragma unroll
        for (int ks = 0; ks < 2; ks++) {
            ABfrag a[2];
#pragma unroll
            for (int m = 0; m < 2; m++) {
                const int rr = 32 * wm + 16 * m + c;        // rr&7 == c&7
                const int j0 = ks * 8 + q * 2;
                const float4 f0 = *(const float4*)&Lf[d][rr * 64 + ((j0    ) ^ (c & 7)) * 4];
                const float4 f1 = *(const float4*)&Lf[d][rr * 64 + ((j0 + 1) ^ (c & 7)) * 4];
                a[m].u[0] = pack_bf16x2(f0.x, f0.y);
                a[m].u[1] = pack_bf16x2(f0.z, f0.w);
                a[m].u[2] = pack_bf16x2(f1.x, f1.y);
                a[m].u[3] = pack_bf16x2(f1.z, f1.w);
            }
#pragma unroll
            for (int ct = 0; ct < 4; ct++) {
                const int n  = 64 * wn + 16 * ct + c;
                const int gl = ks * 4 + q;
                bfrag8 b = *(const bfrag8*)&As[d][n * 8 + (gl ^ (n & 7))];
#pragma unroll
                for (int m = 0; m < 2; m++)
                    acc[m][ct] = __builtin_amdgcn_mfma_f32_16x16x32_bf16(a[m].b, b, acc[m][ct], 0, 0, 0);
            }
        }
    };

    // ---- 2-phase pipeline ----
    int cur = 0;
    stage(0, kc0);
    __syncthreads();                          // prologue drain (exposed once)
    for (int t = 0; t < kpb - 1; t++) {
        stage(cur ^ 1, kc0 + (t + 1) * 64);   // issue next tile FIRST
        compute(cur);                          // overlap: loads land under MFMA
        __syncthreads();                       // one drain+barrier per K-step
        cur ^= 1;
    }
    compute(cur);                              // last tile, no prefetch

    // C/D layout (verified): row = 4q + r within tile, col = c.
    float* P = partials + ((size_t)split * N_ROWS * 128);
    const int cb = 64 * wn + c;
#pragma unroll
    for (int m = 0; m < 2; m++) {
        const int rb = row0 + 32 * wm + 16 * m + 4 * q;
#pragma unroll
        for (int ct = 0; ct < 4; ct++)
#pragma unroll
            for (int r = 0; r < 4; r++)
                P[(size_t)(rb + r) * 128 + cb + 16 * ct] = acc[m][ct][r];
    }
}

// ---------------------------------------------------------------------------
// Kernel 1b: reduce S partials, sign -> 128-bit key -> 64-bit fold
// (R0-verified, unchanged).
// ---------------------------------------------------------------------------
__global__ void __launch_bounds__(256)
reduce_pack(const float* __restrict__ partials, u64* __restrict__ folded, int S) {
    const int row  = blockIdx.x * 4 + (threadIdx.x >> 6);
    const int lane = threadIdx.x & 63;
    float s0 = 0.f, s1 = 0.f;
    for (int s = 0; s < S; s++) {
        const float* P = partials + ((size_t)s * N_ROWS * 128) + (size_t)row * 128;
        s0 += P[lane];
        s1 += P[lane + 64];
    }
    u64 b0 = __ballot(s0 > 0.0f);
    u64 b1 = __ballot(s1 > 0.0f);
    if (lane == 0) folded[row] = b0 ^ b1;
}

// ---------------------------------------------------------------------------
// Kernel 2: ordered duplicate count, LDS-staged keys, load-balanced rows
// (verified, unchanged).
// ---------------------------------------------------------------------------
__global__ void __launch_bounds__(512)
count_rows(const u64* __restrict__ folded, float* __restrict__ out) {
    __shared__ u64 K[N_ROWS];
    const int tid = threadIdx.x;
    for (int i = tid; i < N_ROWS; i += 512) K[i] = folded[i];
    __syncthreads();

    const int g    = blockIdx.x * 8 + (tid >> 6);   // 0..2047
    const int lane = tid & 63;
    int rows[4];
    u64 my[4];
    int cnt[4] = {0, 0, 0, 0};
#pragma unroll
    for (int r = 0; r < 4; r++) {
        rows[r] = g + 2048 * r;
        my[r] = K[rows[r]];
    }
    const int maxrow = rows[3];
    for (int j = lane; j <= maxrow; j += 64) {
        u64 k = K[j];
#pragma unroll
        for (int r = 0; r < 4; r++)
            cnt[r] += (int)((j <= rows[r]) & (k == my[r]));
    }
#pragma unroll
    for (int r = 0; r < 4; r++) {
        int v = cnt[r];
#pragma unroll
        for (int o = 32; o; o >>= 1) v += __shfl_xor(v, o, 64);
        if (lane == 0) out[rows[r]] = rsqrtf((float)v);
    }
}

extern "C" void kernel_launch(void* const* d_in, const int* in_sizes, int n_in,
                              void* d_out, int out_size, void* d_ws, size_t ws_size,
                              hipStream_t stream) {
    const float* latent = (const float*)d_in[0];   // [128,64,4096] fp32
    const float* A      = (const float*)d_in[1];   // [128,4096] fp32
    float* out          = (float*)d_out;           // [8192] fp32

    uint32_t* A_sw = (uint32_t*)d_ws;                                   // 1 MB
    u64* folded = (u64*)((char*)d_ws + (1 << 20));                      // 64 KB
    float* partials = (float*)((char*)d_ws + (1 << 20) + (1 << 16));    // S * 4 MB

    const size_t base = (1 << 20) + (1 << 16);
    const size_t per_split = (size_t)N_ROWS * 128 * sizeof(float);      // 4 MB
    int S = 1;
    if (ws_size >= base + 4 * per_split)      S = 4;
    else if (ws_size >= base + 2 * per_split) S = 2;

    prep_A<<<256, 256, 0, stream>>>(A, A_sw);
    gemm_split64_db<<<dim3(S, 128), 256, 0, stream>>>(latent, A_sw, partials, 64 / S);
    reduce_pack<<<2048, 256, 0, stream>>>(partials, folded, S);
    count_rows<<<256, 512, 0, stream>>>(folded, out);
}

// Round 19
// 223.787 us; speedup vs baseline: 1.0212x; 1.0212x over previous
//
#include <hip/hip_runtime.h>
#include <stdint.h>

#define D_DIM 4096
#define N_ROWS 8192

typedef __attribute__((ext_vector_type(8))) short bfrag8;
typedef __attribute__((ext_vector_type(4))) float facc4;
typedef unsigned long long u64;

union ABfrag { uint32_t u[4]; bfrag8 b; };

__device__ __forceinline__ uint32_t pack_bf16x2(float lo, float hi) {
    union { float f; uint32_t u; } a, b;
    a.f = lo; b.f = hi;
    return (b.u & 0xFFFF0000u) | (a.u >> 16);   // truncate-to-bf16
}

// ---------------------------------------------------------------------------
// Kernel 0: A fp32 -> bf16, XOR-swizzled per-K-chunk image (verified).
// ---------------------------------------------------------------------------
__global__ void __launch_bounds__(256)
prep_A(const float* __restrict__ A, uint32_t* __restrict__ A_sw) {
    const int S = blockIdx.x * 256 + threadIdx.x;  // 0..65535
    const int c = S >> 10;
    const int s = S & 1023;
    const int n = s >> 3;
    const int g = (s & 7) ^ (n & 7);
    const float* src = A + (size_t)n * D_DIM + c * 64 + g * 8;
    float4 f0 = *(const float4*)(src);
    float4 f1 = *(const float4*)(src + 4);
    uint4 o;
    o.x = pack_bf16x2(f0.x, f0.y);
    o.y = pack_bf16x2(f0.z, f0.w);
    o.z = pack_bf16x2(f1.x, f1.y);
    o.w = pack_bf16x2(f1.z, f1.w);
    *(uint4*)(A_sw + (size_t)S * 4) = o;
}

// ---------------------------------------------------------------------------
// Kernel 1: split-K GEMM, BM=64, all staging via global_load_lds.
// REVERT to the R17 best-measured kernel (223.4 us), byte-identical.
// Session evidence: R14/R17 proved gload_lds staging (un-sinkable loads)
// is the one real win; R17 proved blocks/CU not binding (2==4); R18
// proved 2-phase dbuf is null-to-negative on this structure (matches
// m99/m100: implicit wave-level overlap already captures it).
// Swizzle (both-sides rule, HW-verified): LDS 16B-slot j of row r holds
// L[r][j ^ (r&7)]; write src j_src=(lane&15)^(r&7); read j0^(c&7).
// Grid (8,128) = 1024 blocks = 4 blocks/CU, LDS 32 KB.
// ---------------------------------------------------------------------------
__global__ void __launch_bounds__(256, 2)
gemm_split64(const float* __restrict__ L, const uint32_t* __restrict__ A_sw,
             float* __restrict__ partials, int kpb) {
    __shared__ uint32_t Lf[4096];     // 16 KB: 64 rows x 16 slots x 16B (fp32)
    __shared__ uint4    As[1024];     // 16 KB: B chunk (verified swizzled image)

    const int tid  = threadIdx.x;
    const int wave = tid >> 6;
    const int lane = tid & 63;
    const int split = blockIdx.x;
    const int row0 = blockIdx.y * 64;
    const int c  = lane & 15;
    const int q  = lane >> 4;
    const int wm = wave >> 1;         // 32-row half
    const int wn = wave & 1;          // 64-col half

    // L-staging geometry (wave-uniform dst, per-lane swizzled src).
    const int lrow_lo = wave * 4 + (lane >> 4);          // 0..15
    const int js      = (lane & 15) ^ (lrow_lo & 7);     // src 16B-slot in row
    const float* lsrc0 = L + (size_t)(row0 + lrow_lo) * D_DIM + js * 4;

    facc4 acc[2][4];
#pragma unroll
    for (int m = 0; m < 2; m++)
#pragma unroll
        for (int ct = 0; ct < 4; ct++) acc[m][ct] = (facc4){0.f, 0.f, 0.f, 0.f};

    const int kc0 = split * kpb * 64;
    const int kc1 = kc0 + kpb * 64;
    for (int kc = kc0; kc < kc1; kc += 64) {
        // B: 16 KB via 4 global_load_lds per wave (verified path).
        const uint32_t* gA = A_sw + (size_t)(kc >> 6) * 4096;
#pragma unroll
        for (int i = 0; i < 4; i++) {
            const int slot0 = wave * 256 + i * 64;
            __builtin_amdgcn_global_load_lds(
                (const __attribute__((address_space(1))) uint32_t*)(gA + (slot0 + lane) * 4),
                (__attribute__((address_space(3))) uint32_t*)(&As[slot0]),
                16, 0, 0);
        }
        // L: 16 KB raw fp32 via 4 global_load_lds per wave, source-swizzled.
#pragma unroll
        for (int i = 0; i < 4; i++) {
            const uint32_t* src = (const uint32_t*)(lsrc0 + (size_t)(i * 16) * D_DIM + kc);
            __builtin_amdgcn_global_load_lds(
                (const __attribute__((address_space(1))) uint32_t*)src,
                (__attribute__((address_space(3))) uint32_t*)(&Lf[(i * 256 + wave * 64) * 4]),
                16, 0, 0);
        }
        __syncthreads();

#pragma unroll
        for (int ks = 0; ks < 2; ks++) {
            // a-frags: 2x ds_read_b128 fp32 (swizzled slots) + 4 packs each.
            ABfrag a[2];
#pragma unroll
            for (int m = 0; m < 2; m++) {
                const int rr = 32 * wm + 16 * m + c;        // rr&7 == c&7
                const int j0 = ks * 8 + q * 2;
                const float4 f0 = *(const float4*)&Lf[rr * 64 + ((j0    ) ^ (c & 7)) * 4];
                const float4 f1 = *(const float4*)&Lf[rr * 64 + ((j0 + 1) ^ (c & 7)) * 4];
                a[m].u[0] = pack_bf16x2(f0.x, f0.y);
                a[m].u[1] = pack_bf16x2(f0.z, f0.w);
                a[m].u[2] = pack_bf16x2(f1.x, f1.y);
                a[m].u[3] = pack_bf16x2(f1.z, f1.w);
            }
#pragma unroll
            for (int ct = 0; ct < 4; ct++) {
                const int n  = 64 * wn + 16 * ct + c;
                const int gl = ks * 4 + q;
                bfrag8 b = *(const bfrag8*)&As[n * 8 + (gl ^ (n & 7))];
#pragma unroll
                for (int m = 0; m < 2; m++)
                    acc[m][ct] = __builtin_amdgcn_mfma_f32_16x16x32_bf16(a[m].b, b, acc[m][ct], 0, 0, 0);
            }
        }
        __syncthreads();
    }

    // C/D layout (verified): row = 4q + r within tile, col = c.
    float* P = partials + ((size_t)split * N_ROWS * 128);
    const int cb = 64 * wn + c;
#pragma unroll
    for (int m = 0; m < 2; m++) {
        const int rb = row0 + 32 * wm + 16 * m + 4 * q;
#pragma unroll
        for (int ct = 0; ct < 4; ct++)
#pragma unroll
            for (int r = 0; r < 4; r++)
                P[(size_t)(rb + r) * 128 + cb + 16 * ct] = acc[m][ct][r];
    }
}

// ---------------------------------------------------------------------------
// Kernel 1b: reduce S partials, sign -> 128-bit key -> 64-bit fold
// (R0-verified, unchanged).
// ---------------------------------------------------------------------------
__global__ void __launch_bounds__(256)
reduce_pack(const float* __restrict__ partials, u64* __restrict__ folded, int S) {
    const int row  = blockIdx.x * 4 + (threadIdx.x >> 6);
    const int lane = threadIdx.x & 63;
    float s0 = 0.f, s1 = 0.f;
    for (int s = 0; s < S; s++) {
        const float* P = partials + ((size_t)s * N_ROWS * 128) + (size_t)row * 128;
        s0 += P[lane];
        s1 += P[lane + 64];
    }
    u64 b0 = __ballot(s0 > 0.0f);
    u64 b1 = __ballot(s1 > 0.0f);
    if (lane == 0) folded[row] = b0 ^ b1;
}

// ---------------------------------------------------------------------------
// Kernel 2: ordered duplicate count, LDS-staged keys, load-balanced rows
// (verified, unchanged).
// ---------------------------------------------------------------------------
__global__ void __launch_bounds__(512)
count_rows(const u64* __restrict__ folded, float* __restrict__ out) {
    __shared__ u64 K[N_ROWS];
    const int tid = threadIdx.x;
    for (int i = tid; i < N_ROWS; i += 512) K[i] = folded[i];
    __syncthreads();

    const int g    = blockIdx.x * 8 + (tid >> 6);   // 0..2047
    const int lane = tid & 63;
    int rows[4];
    u64 my[4];
    int cnt[4] = {0, 0, 0, 0};
#pragma unroll
    for (int r = 0; r < 4; r++) {
        rows[r] = g + 2048 * r;
        my[r] = K[rows[r]];
    }
    const int maxrow = rows[3];
    for (int j = lane; j <= maxrow; j += 64) {
        u64 k = K[j];
#pragma unroll
        for (int r = 0; r < 4; r++)
            cnt[r] += (int)((j <= rows[r]) & (k == my[r]));
    }
#pragma unroll
    for (int r = 0; r < 4; r++) {
        int v = cnt[r];
#pragma unroll
        for (int o = 32; o; o >>= 1) v += __shfl_xor(v, o, 64);
        if (lane == 0) out[rows[r]] = rsqrtf((float)v);
    }
}

extern "C" void kernel_launch(void* const* d_in, const int* in_sizes, int n_in,
                              void* d_out, int out_size, void* d_ws, size_t ws_size,
                              hipStream_t stream) {
    const float* latent = (const float*)d_in[0];   // [128,64,4096] fp32
    const float* A      = (const float*)d_in[1];   // [128,4096] fp32
    float* out          = (float*)d_out;           // [8192] fp32

    uint32_t* A_sw = (uint32_t*)d_ws;                                   // 1 MB
    u64* folded = (u64*)((char*)d_ws + (1 << 20));                      // 64 KB
    float* partials = (float*)((char*)d_ws + (1 << 20) + (1 << 16));    // S * 4 MB

    const size_t base = (1 << 20) + (1 << 16);
    const size_t per_split = (size_t)N_ROWS * 128 * sizeof(float);      // 4 MB
    int S = 1;
    if (ws_size >= base + 8 * per_split)      S = 8;
    else if (ws_size >= base + 4 * per_split) S = 4;
    else if (ws_size >= base + 2 * per_split) S = 2;

    prep_A<<<256, 256, 0, stream>>>(A, A_sw);
    gemm_split64<<<dim3(S, 128), 256, 0, stream>>>(latent, A_sw, partials, 64 / S);
    reduce_pack<<<2048, 256, 0, stream>>>(partials, folded, S);
    count_rows<<<256, 512, 0, stream>>>(folded, out);
}